// Round 8
// baseline (249.718 us; speedup 1.0000x reference)
//
#include <hip/hip_runtime.h>
#include <hip/hip_bf16.h>

#define B_  2
#define T_  2048
#define D_  1024
#define H_  16
#define KH_ 4
#define DH_ 64

typedef __attribute__((ext_vector_type(8))) short bf16x8;   // 8 bf16 = 4 VGPRs
typedef __attribute__((ext_vector_type(4))) float f32x4;

// log2(e)/8: folded into Q at projection time so softmax is p = exp2(s_raw).
#define QSCALE 0.18033688011112043f

#if defined(__has_builtin)
#  if __has_builtin(__builtin_amdgcn_exp2f)
#    define EXP2F(x) __builtin_amdgcn_exp2f(x)
#  endif
#endif
#ifndef EXP2F
#  define EXP2F(x) exp2f(x)
#endif

// fp32 -> bf16 RNE (scalar, for prep paths where cvt_pk doesn't fit)
__device__ __forceinline__ unsigned short f2bf(float f) {
  union { float f; unsigned int u; } v; v.f = f;
  return (unsigned short)((v.u + 0x7FFFu + ((v.u >> 16) & 1u)) >> 16);
}
// packed fp32x2 -> bf16x2 via v_cvt_pk_bf16_f32 (1 VALU op)
__device__ __forceinline__ unsigned int pk2(float a, float b) {
  union { __hip_bfloat162 h2; unsigned int u; } v;
  v.h2 = __float22bfloat162_rn(make_float2(a, b));
  return v.u;
}

// async global->LDS, 16B per lane. LDS dest = wave-uniform base + lane*16;
// global source is per-lane (pre-swizzled source pattern, m173/rule #21).
__device__ __forceinline__ void g2l16(const void* g, void* l) {
  __builtin_amdgcn_global_load_lds(
      (const __attribute__((address_space(1))) void*)g,
      (__attribute__((address_space(3))) void*)l, 16, 0, 0);
}

// d-slot permutation: slot(d) = (d&15)*4 + (d>>4). Applied consistently to
// Q/K d-dims (QK contraction invariant), att per-head d-dim + WoT k-rows
// (outproj contraction invariant). Exact.
//
// V key-slot permutation (attn swapped-QK in-register P): slot g (0..63)
// holds key tok(g) with bit map  tok5<-g5, tok4<-g2, tok3:2<-g4:3,
// tok1:0<-g1:0.  tok5<-g5 means the permutation acts WITHIN each 32-key
// half -> compatible with the 2x2 wave split (wk owns one 32-half; per-lane
// P packing elem j = ct2*4+r is unchanged).

// ---------------------------------------------------------------------------
// Merged prep (one launch). [UNCHANGED]
// ---------------------------------------------------------------------------
__global__ __launch_bounds__(256) void prep_kernel(
    const float* __restrict__ x,  const float* __restrict__ Wq,
    const float* __restrict__ Wk, const float* __restrict__ Wv,
    const float* __restrict__ Wo,
    short* __restrict__ xb, short* __restrict__ WT, short* __restrict__ WoT,
    float2* __restrict__ tbl) {
  __shared__ short Ts[64 * 72];
  const int bid = blockIdx.x, tid = threadIdx.x;

  if (bid < 2048) {                             // ---- x -> bf16
    const size_t i8 = ((size_t)bid * 256 + tid) * 8;
    const float4 a = *(const float4*)&x[i8];
    const float4 b = *(const float4*)&x[i8 + 4];
    uint4 p; p.x = pk2(a.x, a.y); p.y = pk2(a.z, a.w);
    p.z = pk2(b.x, b.y); p.w = pk2(b.z, b.w);
    *(uint4*)&xb[i8] = p;
  } else if (bid < 2688) {                      // ---- WT / WoT transpose
    const bool isW = bid < 2432;
    const int idx = isW ? (bid - 2048) : (bid - 2432);
    const int n0 = (idx >> 4) * 64, k0 = (idx & 15) * 64;
    const float* src; int ncols, c0; short* dst;
    if (isW) {
      dst = WT;
      if (n0 < 1024)      { src = Wq; ncols = 1024; c0 = n0; }
      else if (n0 < 1280) { src = Wk; ncols = 256;  c0 = n0 - 1024; }
      else                { src = Wv; ncols = 256;  c0 = n0 - 1280; }
    } else { dst = WoT; src = Wo; ncols = 1024; c0 = n0; }
    for (int i = tid; i < 1024; i += 256) {
      const int kr = i >> 4, c4 = (i & 15) << 2;
      const int kc = isW ? kr : ((kr & 15) * 4 + (kr >> 4));
      const float4 w = *(const float4*)&src[(size_t)(k0 + kr) * ncols + c0 + c4];
      Ts[(c4 + 0) * 72 + kc] = (short)f2bf(w.x);
      Ts[(c4 + 1) * 72 + kc] = (short)f2bf(w.y);
      Ts[(c4 + 2) * 72 + kc] = (short)f2bf(w.z);
      Ts[(c4 + 3) * 72 + kc] = (short)f2bf(w.w);
    }
    __syncthreads();
    for (int c = tid; c < 512; c += 256) {
      const int nr = c >> 3, c8 = (c & 7) * 8;
      *(bf16x8*)&dst[(size_t)(n0 + nr) * 1024 + k0 + c8] =
          *(const bf16x8*)&Ts[nr * 72 + c8];
    }
  } else {                                      // ---- RoPE table
    const int e = (bid - 2688) * 256 + tid;     // 65536 entries
    const int t = e >> 5, i2 = e & 31;
    const float freq = exp2f(-(float)(2 * i2) * (18.931568569324174f / 64.0f));
    float sn, cs; sincosf((float)t * freq, &sn, &cs);
    tbl[e] = make_float2(cs, sn);
  }
}

// ---------------------------------------------------------------------------
// Kernel 1: QKV projection [REVERTED to round-6 exact code — best measured
// "rest" config]: 128x64 tiles, 2-phase BK=64 double-buffered counted-vmcnt
// loop, XCD-chunked grid 768.
// ---------------------------------------------------------------------------
__global__ __launch_bounds__(256) void qkv_mfma_kernel(
    const short* __restrict__ xb, const short* __restrict__ WT,
    const float2* __restrict__ tbl,
    short* __restrict__ qo, short* __restrict__ ko, short* __restrict__ vt) {
  __shared__ short Xsh[2][128 * 64];
  __shared__ short Wth[2][64 * 64];
  const int tid = threadIdx.x;
  const int lane = tid & 63, w = tid >> 6;
  const int lm = lane & 15, quad = lane >> 4;
  const int bid = blockIdx.x;
  const int xcd = bid & 7, slot = bid >> 3;     // slot 0..95
  const int m0 = (xcd * 4 + (slot & 3)) * 128;  // 0..3968
  const int n0 = (slot >> 2) * 64;              // 0..1472

  f32x4 acc[2][4];
  #pragma unroll
  for (int sm = 0; sm < 2; ++sm)
    #pragma unroll
    for (int ct = 0; ct < 4; ++ct) acc[sm][ct] = (f32x4){0.f, 0.f, 0.f, 0.f};

  auto stage = [&](int kt, int bsel) {
    #pragma unroll
    for (int u = 0; u < 4; ++u) {               // Xs: 128 rows
      const int r = u * 32 + w * 8 + (lane >> 3);
      const int sb = (lane & 7) ^ (r & 7);
      g2l16(&xb[(size_t)(m0 + r) * 1024 + kt * 64 + sb * 8],
            &Xsh[bsel][(u * 32 + w * 8) * 64]);
    }
    #pragma unroll
    for (int u = 0; u < 2; ++u) {               // Wt: 64 rows
      const int r = u * 32 + w * 8 + (lane >> 3);
      const int sb = (lane & 7) ^ (r & 7);
      g2l16(&WT[(size_t)(n0 + r) * 1024 + kt * 64 + sb * 8],
            &Wth[bsel][(u * 32 + w * 8) * 64]);
    }
  };

  stage(0, 0);
  for (int kt = 0; kt < 16; ++kt) {
    const int bsel = kt & 1;
    if (kt < 15) {
      stage(kt + 1, bsel ^ 1);
      asm volatile("s_waitcnt vmcnt(6)" ::: "memory");
    } else {
      asm volatile("s_waitcnt vmcnt(0)" ::: "memory");
    }
    __builtin_amdgcn_s_barrier();
    __builtin_amdgcn_sched_barrier(0);
    #pragma unroll
    for (int s2 = 0; s2 < 2; ++s2) {
      bf16x8 bfr[4];
      #pragma unroll
      for (int ct = 0; ct < 4; ++ct)
        bfr[ct] = *(const bf16x8*)&Wth[bsel][(ct * 16 + lm) * 64 +
                                            (((s2 * 4 + quad) ^ (lm & 7)) << 3)];
      #pragma unroll
      for (int sm = 0; sm < 2; ++sm) {
        const bf16x8 a = *(const bf16x8*)&Xsh[bsel][(w * 32 + sm * 16 + lm) * 64 +
                                            (((s2 * 4 + quad) ^ (lm & 7)) << 3)];
        #pragma unroll
        for (int ct = 0; ct < 4; ++ct)
          acc[sm][ct] =
              __builtin_amdgcn_mfma_f32_16x16x32_bf16(a, bfr[ct], acc[sm][ct], 0, 0, 0);
      }
    }
    __builtin_amdgcn_sched_barrier(0);
    __builtin_amdgcn_s_barrier();
  }

  if (n0 < 1280) {                              // ---- Q or K: RoPE + b64 store
    const bool isQ = n0 < 1024;
    short* outp = isQ ? qo : ko;
    const int base = isQ ? n0 : n0 - 1024;
    const int nh = isQ ? H_ : KH_;
    const int hh = base >> 6;
    const float post = isQ ? QSCALE : 1.0f;
    #pragma unroll
    for (int sm = 0; sm < 2; ++sm)
      #pragma unroll
      for (int r = 0; r < 4; ++r) {
        const int row = m0 + w * 32 + sm * 16 + quad * 4 + r;
        const int b = row >> 11, t = row & 2047;
        float v4[4];
        #pragma unroll
        for (int ct = 0; ct < 4; ++ct) {
          float val = acc[sm][ct][r];
          const float other = __shfl_xor(val, 1);
          const int ci = ct * 16 + lm;
          const float2 cs = tbl[t * 32 + (ci >> 1)];
          val = ((ci & 1) == 0) ? (val * cs.x - other * cs.y)
                                : (val * cs.x + other * cs.y);
          v4[ct] = val * post;
        }
        uint2 st; st.x = pk2(v4[0], v4[1]); st.y = pk2(v4[2], v4[3]);
        *(uint2*)&outp[((size_t)(b * nh + hh) * T_ + t) * DH_ + lm * 4] = st;
      }
  } else {                                      // ---- V: LDS-bounce transpose
    short* XsF = &Xsh[0][0];
    __syncthreads();
    #pragma unroll
    for (int sm = 0; sm < 2; ++sm)
      #pragma unroll
      for (int r = 0; r < 4; ++r)
        #pragma unroll
        for (int ct = 0; ct < 4; ++ct)
          XsF[(w * 32 + sm * 16 + quad * 4 + r) * 72 + ct * 16 + lm] =
              (short)f2bf(acc[sm][ct][r]);
    __syncthreads();
    const int kh = (n0 - 1280) >> 6;
    const int b = m0 >> 11, t0 = m0 & 2047;
    short* vb = vt + (size_t)(b * KH_ + kh) * DH_ * T_;
    for (int c = tid; c < 1024; c += 256) {
      const int d = c >> 4, c8 = (c & 15) * 8;
      short tmp[8];
      #pragma unroll
      for (int j = 0; j < 8; ++j) {
        const int s = c8 + j, sg = s & 63;
        const int tok = (s & 64) | (sg & 35) | (((sg >> 2) & 1) << 4) |
                        (((sg >> 3) & 3) << 2);
        tmp[j] = XsF[tok * 72 + d];
      }
      *(bf16x8*)&vb[(size_t)d * T_ + t0 + c8] = *(bf16x8*)tmp;
    }
  }
}

// ---------------------------------------------------------------------------
// Kernel 2: causal flash attention, swapped-QK in-register-P, 2x2 WAVE
// SPLIT (wq, wk): each wave = 32 q-rows x its 32-key half. Halves per-wave
// LDS reads (16 -> 8 b128/step: Ks 4, Vts 4 hoisted+reused across sm) —
// attacks the CU-level LDS-pipe bound (arithmetic: 16 reads x 12cyc x 16
// waves ~= 3072 cyc/step-window vs MFMA 350 -> predicted MfmaUtil ~11-17%,
// measured 17.6%) WITHOUT sacrificing wave count (round-4's failure mode).
// V key-slot permutation acts within 32-halves (tok5<-g5) -> per-lane P
// packing (elem j = ct2*4+r) and all masks carry over unchanged. Keys-
// contraction split healed by one-time cross-wk reduction through reused
// LDS at epilogue (no online max -> partials directly additive). Grid 1024
// = 4/CU, qt interleave = constant 66 steps/CU; s_setprio around MFMA (T5).
// ---------------------------------------------------------------------------
__global__ __launch_bounds__(256, 4) void attn_mfma_kernel(
    const short* __restrict__ q, const short* __restrict__ k,
    const short* __restrict__ vt, short* __restrict__ att) {
  __shared__ __align__(16) short SMEM[128 * 72 + 64 * 136];  // Ks | Vts, 35840B
  short* Ks = SMEM;
  short* Vts = SMEM + 128 * 72;                 // [d][slot 0..127]

  const int bx = blockIdx.x;
  const int jj = bx & 255, c2 = bx >> 8;
  int qt = (c2 & 1) ? (jj >> 3) : (31 - (jj >> 3));   // heavy-first in chunk 0
  const int hb = (jj & 7) | (c2 << 3);
  const int h = hb >> 1, b = hb & 1;
  const int kh = h >> 2;                        // n_rep = 4
  const int tid = threadIdx.x;
  const int lane = tid & 63, w = tid >> 6;
  const int wq = w >> 1, wk = w & 1;            // 2x2 wave grid
  const int lm = lane & 15, quad = lane >> 4;
  const int q0 = qt * 64;

  const short* qb = q + (size_t)(b * H_ + h) * T_ * DH_;
  const short* kb = k + (size_t)(b * KH_ + kh) * T_ * DH_;
  const short* vb = vt + (size_t)(b * KH_ + kh) * DH_ * T_;

  bf16x8 ones;
  #pragma unroll
  for (int i = 0; i < 8; ++i) ones[i] = (short)0x3F80;  // bf16 1.0

  bf16x8 aq[2][2];                              // [sm][s2], 32 q-rows
  #pragma unroll
  for (int sm = 0; sm < 2; ++sm)
    #pragma unroll
    for (int s2 = 0; s2 < 2; ++s2)
      aq[sm][s2] = *(const bf16x8*)&qb[(size_t)(q0 + wq * 32 + sm * 16 + lm) * 64 +
                                       s2 * 32 + quad * 8];

  bf16x8 pk[4], pv[4];
  #pragma unroll
  for (int u = 0; u < 4; ++u) {                 // preload r2=0 (128 keys)
    const int c = tid + u * 256;
    const int row = c >> 3, c8 = (c & 7) * 8;
    pk[u] = *(const bf16x8*)&kb[(size_t)row * 64 + c8];
    const int d = c >> 4, c16 = (c & 15) * 8;
    pv[u] = *(const bf16x8*)&vb[(size_t)d * T_ + c16];
  }

  f32x4 oacc[2][4], lacc[2];
  #pragma unroll
  for (int sm = 0; sm < 2; ++sm) {
    #pragma unroll
    for (int ct = 0; ct < 4; ++ct) oacc[sm][ct] = (f32x4){0.f, 0.f, 0.f, 0.f};
    lacc[sm] = (f32x4){0.f, 0.f, 0.f, 0.f};
  }

  // one 64-key tile-step; this wave covers keys j*64 + wk*32 .. +32
  auto step = [&](int j, bool diag) {
    f32x4 sacc[2][2];                           // [sm][ct2]
    #pragma unroll
    for (int sm = 0; sm < 2; ++sm)
      #pragma unroll
      for (int ct2 = 0; ct2 < 2; ++ct2) sacc[sm][ct2] = (f32x4){0.f, 0.f, 0.f, 0.f};
    __builtin_amdgcn_s_setprio(1);
    #pragma unroll
    for (int s2 = 0; s2 < 2; ++s2) {
      #pragma unroll
      for (int ct2 = 0; ct2 < 2; ++ct2) {
        const int kg = wk * 2 + ct2;            // 16-key group 0..3
        if (diag && kg > wq * 2 + 1) continue;  // masked for both sm
        const bf16x8 bb = *(const bf16x8*)&Ks[(j * 64 + wk * 32 + ct2 * 16 + lm) * 72 +
                                              s2 * 32 + quad * 8];
        #pragma unroll
        for (int sm = 0; sm < 2; ++sm) {
          if (diag && kg > wq * 2 + sm) continue;
          // swapped operands: D[key][q], q = lane&15
          sacc[sm][ct2] =
              __builtin_amdgcn_mfma_f32_16x16x32_bf16(bb, aq[sm][s2], sacc[sm][ct2], 0, 0, 0);
        }
      }
    }
    __builtin_amdgcn_s_setprio(0);
    // in-lane softmax: sacc[sm][ct2][r] = P[key wk*32+ct2*16+quad*4+r][q wq*32+sm*16+lm]
    unsigned int pd[2][2][2];
    #pragma unroll
    for (int sm = 0; sm < 2; ++sm)
      #pragma unroll
      for (int ct2 = 0; ct2 < 2; ++ct2) {
        const int kg = wk * 2 + ct2, qg = wq * 2 + sm;
        float p[4];
        #pragma unroll
        for (int r = 0; r < 4; ++r) {
          float e;
          if (diag && kg > qg) e = 0.f;         // block fully above diagonal
          else {
            e = EXP2F(sacc[sm][ct2][r]);
            if (diag && kg == qg && (quad * 4 + r) > lm) e = 0.f;  // causal mask
          }
          p[r] = e;
        }
        pd[sm][ct2][0] = pk2(p[0], p[1]);
        pd[sm][ct2][1] = pk2(p[2], p[3]);
      }
    __builtin_amdgcn_s_setprio(1);
    bf16x8 vfr[4];                              // hoisted: reused by both sm
    #pragma unroll
    for (int ct = 0; ct < 4; ++ct)
      vfr[ct] = *(const bf16x8*)&Vts[(ct * 16 + lm) * 136 + j * 64 + wk * 32 + quad * 8];
    #pragma unroll
    for (int sm = 0; sm < 2; ++sm) {
      if (diag && wk * 2 > wq * 2 + sm) continue;  // whole wk-half masked
      union { bf16x8 v; unsigned int u[4]; } pa;   // A elem j = ct2*4+r
      pa.u[0] = pd[sm][0][0]; pa.u[1] = pd[sm][0][1];
      pa.u[2] = pd[sm][1][0]; pa.u[3] = pd[sm][1][1];
      lacc[sm] = __builtin_amdgcn_mfma_f32_16x16x32_bf16(pa.v, ones, lacc[sm], 0, 0, 0);
      #pragma unroll
      for (int ct = 0; ct < 4; ++ct)
        oacc[sm][ct] =
            __builtin_amdgcn_mfma_f32_16x16x32_bf16(pa.v, vfr[ct], oacc[sm][ct], 0, 0, 0);
    }
    __builtin_amdgcn_s_setprio(0);
  };

  auto stage = [&](int r2) {
    __syncthreads();                            // prior K/V LDS reads done
    #pragma unroll
    for (int u = 0; u < 4; ++u) {
      const int c = tid + u * 256;
      const int row = c >> 3, c8 = (c & 7) * 8;
      *(bf16x8*)&Ks[row * 72 + c8] = pk[u];
      const int d = c >> 4, c16 = (c & 15) * 8;
      *(bf16x8*)&Vts[d * 136 + c16] = pv[u];
    }
    __syncthreads();
    const int r2n = (r2 + 2 <= qt) ? (r2 + 2) : r2;   // prefetch next pair
    #pragma unroll
    for (int u = 0; u < 4; ++u) {
      const int c = tid + u * 256;
      const int row = c >> 3, c8 = (c & 7) * 8;
      pk[u] = *(const bf16x8*)&kb[(size_t)(r2n * 64 + row) * 64 + c8];
      const int d = c >> 4, c16 = (c & 15) * 8;
      pv[u] = *(const bf16x8*)&vb[(size_t)d * T_ + r2n * 64 + c16];
    }
  };

  int r2 = 0;
  for (; r2 + 1 <= qt; r2 += 2) {               // full pairs only
    stage(r2);
    step(0, false);                             // never diagonal
    step(1, r2 + 1 == qt);                      // diagonal only on last pair
  }
  if (r2 == qt) {                               // peeled final step (even qt)
    stage(r2);
    step(0, true);
  }

  // ---- cross-wk reduction through reused LDS, then store (wk==0 waves)
  __syncthreads();                              // all waves done with Ks/Vts
  float* LF = (float*)SMEM;                     // 5120 floats = 20KB < 35.8KB
  if (wk == 1) {
    #pragma unroll
    for (int sm = 0; sm < 2; ++sm) {
      #pragma unroll
      for (int ct = 0; ct < 4; ++ct)
        *(f32x4*)&LF[(((wq * 2 + sm) * 4 + ct) * 64 + lane) * 4] = oacc[sm][ct];
      *(f32x4*)&LF[4096 + ((wq * 2 + sm) * 64 + lane) * 4] = lacc[sm];
    }
  }
  __syncthreads();
  if (wk == 0) {
    #pragma unroll
    for (int sm = 0; sm < 2; ++sm) {
      #pragma unroll
      for (int ct = 0; ct < 4; ++ct)
        oacc[sm][ct] += *(const f32x4*)&LF[(((wq * 2 + sm) * 4 + ct) * 64 + lane) * 4];
      lacc[sm] += *(const f32x4*)&LF[4096 + ((wq * 2 + sm) * 64 + lane) * 4];
      #pragma unroll
      for (int r = 0; r < 4; ++r) {
        const int qrow = q0 + wq * 32 + sm * 16 + quad * 4 + r;
        const float inv = 1.f / lacc[sm][r];
        // d ct*16+lm -> slot lm*4+ct (WoT k-rows match): one b64 store
        uint2 st;
        st.x = pk2(oacc[sm][0][r] * inv, oacc[sm][1][r] * inv);
        st.y = pk2(oacc[sm][2][r] * inv, oacc[sm][3][r] * inv);
        *(uint2*)&att[((size_t)b * T_ + qrow) * 1024 + h * 64 + lm * 4] = st;
      }
    }
  }
}

// ---------------------------------------------------------------------------
// Kernel 3: output projection [REVERTED to round-6 exact code]: 128x64
// tiles, 2-phase BK=64 counted-vmcnt loop, XCD-chunked grid 512.
// ---------------------------------------------------------------------------
__global__ __launch_bounds__(256) void outproj_mfma_kernel(
    const short* __restrict__ att, const short* __restrict__ WoT,
    float* __restrict__ out) {
  __shared__ short Xsh[2][128 * 64];
  __shared__ short Wth[2][64 * 64];
  const int tid = threadIdx.x;
  const int lane = tid & 63, w = tid >> 6;
  const int lm = lane & 15, quad = lane >> 4;
  const int bid = blockIdx.x;
  const int xcd = bid & 7, slot = bid >> 3;     // slot 0..63
  const int m0 = (xcd * 4 + (slot & 3)) * 128;
  const int n0 = (slot >> 2) * 64;              // 0..960

  f32x4 acc[2][4];
  #pragma unroll
  for (int sm = 0; sm < 2; ++sm)
    #pragma unroll
    for (int ct = 0; ct < 4; ++ct) acc[sm][ct] = (f32x4){0.f, 0.f, 0.f, 0.f};

  auto stage = [&](int kt, int bsel) {
    #pragma unroll
    for (int u = 0; u < 4; ++u) {
      const int r = u * 32 + w * 8 + (lane >> 3);
      const int sb = (lane & 7) ^ (r & 7);
      g2l16(&att[(size_t)(m0 + r) * 1024 + kt * 64 + sb * 8],
            &Xsh[bsel][(u * 32 + w * 8) * 64]);
    }
    #pragma unroll
    for (int u = 0; u < 2; ++u) {
      const int r = u * 32 + w * 8 + (lane >> 3);
      const int sb = (lane & 7) ^ (r & 7);
      g2l16(&WoT[(size_t)(n0 + r) * 1024 + kt * 64 + sb * 8],
            &Wth[bsel][(u * 32 + w * 8) * 64]);
    }
  };

  stage(0, 0);
  for (int kt = 0; kt < 16; ++kt) {
    const int bsel = kt & 1;
    if (kt < 15) {
      stage(kt + 1, bsel ^ 1);
      asm volatile("s_waitcnt vmcnt(6)" ::: "memory");
    } else {
      asm volatile("s_waitcnt vmcnt(0)" ::: "memory");
    }
    __builtin_amdgcn_s_barrier();
    __builtin_amdgcn_sched_barrier(0);
    #pragma unroll
    for (int s2 = 0; s2 < 2; ++s2) {
      bf16x8 bfr[4];
      #pragma unroll
      for (int ct = 0; ct < 4; ++ct)
        bfr[ct] = *(const bf16x8*)&Wth[bsel][(ct * 16 + lm) * 64 +
                                            (((s2 * 4 + quad) ^ (lm & 7)) << 3)];
      #pragma unroll
      for (int sm = 0; sm < 2; ++sm) {
        const bf16x8 a = *(const bf16x8*)&Xsh[bsel][(w * 32 + sm * 16 + lm) * 64 +
                                            (((s2 * 4 + quad) ^ (lm & 7)) << 3)];
        #pragma unroll
        for (int ct = 0; ct < 4; ++ct)
          acc[sm][ct] =
              __builtin_amdgcn_mfma_f32_16x16x32_bf16(a, bfr[ct], acc[sm][ct], 0, 0, 0);
      }
    }
    __builtin_amdgcn_sched_barrier(0);
    __builtin_amdgcn_s_barrier();
  }

  #pragma unroll
  for (int sm = 0; sm < 2; ++sm)
    #pragma unroll
    for (int r = 0; r < 4; ++r) {
      const int row = m0 + w * 32 + sm * 16 + quad * 4 + r;
      #pragma unroll
      for (int ct = 0; ct < 4; ++ct)
        out[(size_t)row * 1024 + n0 + ct * 16 + lm] = acc[sm][ct][r];
    }
}

extern "C" void kernel_launch(void* const* d_in, const int* in_sizes, int n_in,
                              void* d_out, int out_size, void* d_ws, size_t ws_size,
                              hipStream_t stream) {
  const float* x  = (const float*)d_in[0];
  // d_in[1] = mask: fixed causal tril, handled analytically; never read.
  const float* Wq = (const float*)d_in[2];
  const float* Wk = (const float*)d_in[3];
  const float* Wv = (const float*)d_in[4];
  const float* Wo = (const float*)d_in[5];
  float* out = (float*)d_out;

  short* xb   = (short*)d_ws;
  short* WT   = xb  + (size_t)4194304;          // 1536*1024
  short* WoT  = WT  + (size_t)1572864;          // 1024*1024 (k sigma-permuted)
  short* qb   = WoT + (size_t)1048576;          // 2*16*2048*64 (d sigma-permuted)
  short* kb   = qb  + (size_t)4194304;          // 2*4*2048*64 (d sigma-permuted)
  short* vtb  = kb  + (size_t)1048576;          // 2*4*64*2048 (transposed+permuted)
  short* attb = vtb + (size_t)1048576;          // 2*2048*1024 (d sigma-permuted)
  float2* tbl = (float2*)(attb + (size_t)4194304);  // 2048*32 float2

  prep_kernel<<<dim3(2944), dim3(256), 0, stream>>>(
      x, Wq, Wk, Wv, Wo, xb, WT, WoT, tbl);
  qkv_mfma_kernel<<<dim3(768), dim3(256), 0, stream>>>(xb, WT, tbl, qb, kb, vtb);
  attn_mfma_kernel<<<dim3(1024), dim3(256), 0, stream>>>(qb, kb, vtb, attb);
  outproj_mfma_kernel<<<dim3(512), dim3(256), 0, stream>>>(attb, WoT, out);
}

// Round 9
// 169.357 us; speedup vs baseline: 1.4745x; 1.4745x over previous
//
#include <hip/hip_runtime.h>
#include <hip/hip_bf16.h>

#define B_  2
#define T_  2048
#define D_  1024
#define H_  16
#define KH_ 4
#define DH_ 64

typedef __attribute__((ext_vector_type(8))) short bf16x8;   // 8 bf16 = 4 VGPRs
typedef __attribute__((ext_vector_type(4))) float f32x4;

// log2(e)/8: folded into Q at projection time so softmax is p = exp2(s_raw).
#define QSCALE 0.18033688011112043f

#if defined(__has_builtin)
#  if __has_builtin(__builtin_amdgcn_exp2f)
#    define EXP2F(x) __builtin_amdgcn_exp2f(x)
#  endif
#endif
#ifndef EXP2F
#  define EXP2F(x) exp2f(x)
#endif

// fp32 -> bf16 RNE (scalar, for prep paths where cvt_pk doesn't fit)
__device__ __forceinline__ unsigned short f2bf(float f) {
  union { float f; unsigned int u; } v; v.f = f;
  return (unsigned short)((v.u + 0x7FFFu + ((v.u >> 16) & 1u)) >> 16);
}
// packed fp32x2 -> bf16x2 via v_cvt_pk_bf16_f32 (1 VALU op)
__device__ __forceinline__ unsigned int pk2(float a, float b) {
  union { __hip_bfloat162 h2; unsigned int u; } v;
  v.h2 = __float22bfloat162_rn(make_float2(a, b));
  return v.u;
}

// async global->LDS, 16B per lane. LDS dest = wave-uniform base + lane*16;
// global source is per-lane (pre-swizzled source pattern, m173/rule #21).
__device__ __forceinline__ void g2l16(const void* g, void* l) {
  __builtin_amdgcn_global_load_lds(
      (const __attribute__((address_space(1))) void*)g,
      (__attribute__((address_space(3))) void*)l, 16, 0, 0);
}

// d-slot permutation: slot(d) = (d&15)*4 + (d>>4). Applied consistently to
// Q/K d-dims (QK contraction invariant), att per-head d-dim + WoT k-rows
// (outproj contraction invariant). Exact.
//
// V key-slot permutation (attn swapped-QK in-register P): slot g (0..63)
// holds key tok(g) with bit map  tok5<-g5, tok4<-g2, tok3:2<-g4:3,
// tok1:0<-g1:0.  This makes the PV A-operand buildable from each lane's OWN
// exp'd QK outputs (no cross-lane exchange, no P LDS bounce).

// ---------------------------------------------------------------------------
// Merged prep (one launch). [UNCHANGED]
// ---------------------------------------------------------------------------
__global__ __launch_bounds__(256) void prep_kernel(
    const float* __restrict__ x,  const float* __restrict__ Wq,
    const float* __restrict__ Wk, const float* __restrict__ Wv,
    const float* __restrict__ Wo,
    short* __restrict__ xb, short* __restrict__ WT, short* __restrict__ WoT,
    float2* __restrict__ tbl) {
  __shared__ short Ts[64 * 72];
  const int bid = blockIdx.x, tid = threadIdx.x;

  if (bid < 2048) {                             // ---- x -> bf16
    const size_t i8 = ((size_t)bid * 256 + tid) * 8;
    const float4 a = *(const float4*)&x[i8];
    const float4 b = *(const float4*)&x[i8 + 4];
    uint4 p; p.x = pk2(a.x, a.y); p.y = pk2(a.z, a.w);
    p.z = pk2(b.x, b.y); p.w = pk2(b.z, b.w);
    *(uint4*)&xb[i8] = p;
  } else if (bid < 2688) {                      // ---- WT / WoT transpose
    const bool isW = bid < 2432;
    const int idx = isW ? (bid - 2048) : (bid - 2432);
    const int n0 = (idx >> 4) * 64, k0 = (idx & 15) * 64;
    const float* src; int ncols, c0; short* dst;
    if (isW) {
      dst = WT;
      if (n0 < 1024)      { src = Wq; ncols = 1024; c0 = n0; }
      else if (n0 < 1280) { src = Wk; ncols = 256;  c0 = n0 - 1024; }
      else                { src = Wv; ncols = 256;  c0 = n0 - 1280; }
    } else { dst = WoT; src = Wo; ncols = 1024; c0 = n0; }
    for (int i = tid; i < 1024; i += 256) {
      const int kr = i >> 4, c4 = (i & 15) << 2;
      const int kc = isW ? kr : ((kr & 15) * 4 + (kr >> 4));
      const float4 w = *(const float4*)&src[(size_t)(k0 + kr) * ncols + c0 + c4];
      Ts[(c4 + 0) * 72 + kc] = (short)f2bf(w.x);
      Ts[(c4 + 1) * 72 + kc] = (short)f2bf(w.y);
      Ts[(c4 + 2) * 72 + kc] = (short)f2bf(w.z);
      Ts[(c4 + 3) * 72 + kc] = (short)f2bf(w.w);
    }
    __syncthreads();
    for (int c = tid; c < 512; c += 256) {
      const int nr = c >> 3, c8 = (c & 7) * 8;
      *(bf16x8*)&dst[(size_t)(n0 + nr) * 1024 + k0 + c8] =
          *(const bf16x8*)&Ts[nr * 72 + c8];
    }
  } else {                                      // ---- RoPE table
    const int e = (bid - 2688) * 256 + tid;     // 65536 entries
    const int t = e >> 5, i2 = e & 31;
    const float freq = exp2f(-(float)(2 * i2) * (18.931568569324174f / 64.0f));
    float sn, cs; sincosf((float)t * freq, &sn, &cs);
    tbl[e] = make_float2(cs, sn);
  }
}

// ---------------------------------------------------------------------------
// Kernel 1: QKV projection [round-6 exact code — best measured "rest"]:
// 128x64 tiles, 2-phase BK=64 double-buffered counted-vmcnt loop,
// XCD-chunked grid 768.
// ---------------------------------------------------------------------------
__global__ __launch_bounds__(256) void qkv_mfma_kernel(
    const short* __restrict__ xb, const short* __restrict__ WT,
    const float2* __restrict__ tbl,
    short* __restrict__ qo, short* __restrict__ ko, short* __restrict__ vt) {
  __shared__ short Xsh[2][128 * 64];
  __shared__ short Wth[2][64 * 64];
  const int tid = threadIdx.x;
  const int lane = tid & 63, w = tid >> 6;
  const int lm = lane & 15, quad = lane >> 4;
  const int bid = blockIdx.x;
  const int xcd = bid & 7, slot = bid >> 3;     // slot 0..95
  const int m0 = (xcd * 4 + (slot & 3)) * 128;  // 0..3968
  const int n0 = (slot >> 2) * 64;              // 0..1472

  f32x4 acc[2][4];
  #pragma unroll
  for (int sm = 0; sm < 2; ++sm)
    #pragma unroll
    for (int ct = 0; ct < 4; ++ct) acc[sm][ct] = (f32x4){0.f, 0.f, 0.f, 0.f};

  auto stage = [&](int kt, int bsel) {
    #pragma unroll
    for (int u = 0; u < 4; ++u) {               // Xs: 128 rows
      const int r = u * 32 + w * 8 + (lane >> 3);
      const int sb = (lane & 7) ^ (r & 7);
      g2l16(&xb[(size_t)(m0 + r) * 1024 + kt * 64 + sb * 8],
            &Xsh[bsel][(u * 32 + w * 8) * 64]);
    }
    #pragma unroll
    for (int u = 0; u < 2; ++u) {               // Wt: 64 rows
      const int r = u * 32 + w * 8 + (lane >> 3);
      const int sb = (lane & 7) ^ (r & 7);
      g2l16(&WT[(size_t)(n0 + r) * 1024 + kt * 64 + sb * 8],
            &Wth[bsel][(u * 32 + w * 8) * 64]);
    }
  };

  stage(0, 0);
  for (int kt = 0; kt < 16; ++kt) {
    const int bsel = kt & 1;
    if (kt < 15) {
      stage(kt + 1, bsel ^ 1);
      asm volatile("s_waitcnt vmcnt(6)" ::: "memory");
    } else {
      asm volatile("s_waitcnt vmcnt(0)" ::: "memory");
    }
    __builtin_amdgcn_s_barrier();
    __builtin_amdgcn_sched_barrier(0);
    #pragma unroll
    for (int s2 = 0; s2 < 2; ++s2) {
      bf16x8 bfr[4];
      #pragma unroll
      for (int ct = 0; ct < 4; ++ct)
        bfr[ct] = *(const bf16x8*)&Wth[bsel][(ct * 16 + lm) * 64 +
                                            (((s2 * 4 + quad) ^ (lm & 7)) << 3)];
      #pragma unroll
      for (int sm = 0; sm < 2; ++sm) {
        const bf16x8 a = *(const bf16x8*)&Xsh[bsel][(w * 32 + sm * 16 + lm) * 64 +
                                            (((s2 * 4 + quad) ^ (lm & 7)) << 3)];
        #pragma unroll
        for (int ct = 0; ct < 4; ++ct)
          acc[sm][ct] =
              __builtin_amdgcn_mfma_f32_16x16x32_bf16(a, bfr[ct], acc[sm][ct], 0, 0, 0);
      }
    }
    __builtin_amdgcn_sched_barrier(0);
    __builtin_amdgcn_s_barrier();
  }

  if (n0 < 1280) {                              // ---- Q or K: RoPE + b64 store
    const bool isQ = n0 < 1024;
    short* outp = isQ ? qo : ko;
    const int base = isQ ? n0 : n0 - 1024;
    const int nh = isQ ? H_ : KH_;
    const int hh = base >> 6;
    const float post = isQ ? QSCALE : 1.0f;
    #pragma unroll
    for (int sm = 0; sm < 2; ++sm)
      #pragma unroll
      for (int r = 0; r < 4; ++r) {
        const int row = m0 + w * 32 + sm * 16 + quad * 4 + r;
        const int b = row >> 11, t = row & 2047;
        float v4[4];
        #pragma unroll
        for (int ct = 0; ct < 4; ++ct) {
          float val = acc[sm][ct][r];
          const float other = __shfl_xor(val, 1);
          const int ci = ct * 16 + lm;
          const float2 cs = tbl[t * 32 + (ci >> 1)];
          val = ((ci & 1) == 0) ? (val * cs.x - other * cs.y)
                                : (val * cs.x + other * cs.y);
          v4[ct] = val * post;
        }
        uint2 st; st.x = pk2(v4[0], v4[1]); st.y = pk2(v4[2], v4[3]);
        *(uint2*)&outp[((size_t)(b * nh + hh) * T_ + t) * DH_ + lm * 4] = st;
      }
  } else {                                      // ---- V: LDS-bounce transpose
    short* XsF = &Xsh[0][0];
    __syncthreads();
    #pragma unroll
    for (int sm = 0; sm < 2; ++sm)
      #pragma unroll
      for (int r = 0; r < 4; ++r)
        #pragma unroll
        for (int ct = 0; ct < 4; ++ct)
          XsF[(w * 32 + sm * 16 + quad * 4 + r) * 72 + ct * 16 + lm] =
              (short)f2bf(acc[sm][ct][r]);
    __syncthreads();
    const int kh = (n0 - 1280) >> 6;
    const int b = m0 >> 11, t0 = m0 & 2047;
    short* vb = vt + (size_t)(b * KH_ + kh) * DH_ * T_;
    for (int c = tid; c < 1024; c += 256) {
      const int d = c >> 4, c8 = (c & 15) * 8;
      short tmp[8];
      #pragma unroll
      for (int j = 0; j < 8; ++j) {
        const int s = c8 + j, sg = s & 63;
        const int tok = (s & 64) | (sg & 35) | (((sg >> 2) & 1) << 4) |
                        (((sg >> 3) & 3) << 2);
        tmp[j] = XsF[tok * 72 + d];
      }
      *(bf16x8*)&vb[(size_t)d * T_ + t0 + c8] = *(bf16x8*)tmp;
    }
  }
}

// ---------------------------------------------------------------------------
// Kernel 2: causal flash attention [REVERTED to round-3 exact code — best
// measured attn of the session: 41.1us, 64 VGPR, zero spill. Round-8's 2x2
// wave split needed ~150 VGPR under the 128 cap -> scratch spill (FETCH
// 12.6->62MB, WRITE 9->116MB, 120us). Any future restructure must fit
// 128 VGPR @ 4 blocks/CU]. Swapped-QK in-register-P; grid 1024 = 4/CU;
// qt interleave = constant 66 steps/CU; diag tiles skip masked MFMA blocks
// (wave-uniform); row-sum via MFMA ones-column; reg prefetch for K/V;
// s_setprio(1) around MFMA clusters (T5).
// ---------------------------------------------------------------------------
__global__ __launch_bounds__(256, 4) void attn_mfma_kernel(
    const short* __restrict__ q, const short* __restrict__ k,
    const short* __restrict__ vt, short* __restrict__ att) {
  __shared__ short Ks[128 * 72];
  __shared__ short Vts[64 * 136];               // [d][slot 0..127]

  const int bx = blockIdx.x;
  const int jj = bx & 255, c2 = bx >> 8;
  int qt = (c2 & 1) ? (jj >> 3) : (31 - (jj >> 3));   // heavy-first in chunk 0
  const int hb = (jj & 7) | (c2 << 3);
  const int h = hb >> 1, b = hb & 1;
  const int kh = h >> 2;                        // n_rep = 4
  const int tid = threadIdx.x;
  const int lane = tid & 63, w = tid >> 6;
  const int lm = lane & 15, quad = lane >> 4;
  const int q0 = qt * 64;

  const short* qb = q + (size_t)(b * H_ + h) * T_ * DH_;
  const short* kb = k + (size_t)(b * KH_ + kh) * T_ * DH_;
  const short* vb = vt + (size_t)(b * KH_ + kh) * DH_ * T_;

  bf16x8 ones;
  #pragma unroll
  for (int i = 0; i < 8; ++i) ones[i] = (short)0x3F80;  // bf16 1.0

  bf16x8 aq[2];                                 // kt-invariant Q fragments
  #pragma unroll
  for (int s = 0; s < 2; ++s)                   // direct global load (no LDS)
    aq[s] = *(const bf16x8*)&qb[(size_t)(q0 + w * 16 + lm) * 64 + s * 32 + quad * 8];

  bf16x8 pk[4], pv[4];
  #pragma unroll
  for (int u = 0; u < 4; ++u) {                 // preload r2=0 (128 keys)
    const int c = tid + u * 256;
    const int row = c >> 3, c8 = (c & 7) * 8;
    pk[u] = *(const bf16x8*)&kb[(size_t)row * 64 + c8];
    const int d = c >> 4, c16 = (c & 15) * 8;
    pv[u] = *(const bf16x8*)&vb[(size_t)d * T_ + c16];
  }

  f32x4 oacc[4], lacc;
  #pragma unroll
  for (int i = 0; i < 4; ++i) oacc[i] = (f32x4){0.f, 0.f, 0.f, 0.f};
  lacc = (f32x4){0.f, 0.f, 0.f, 0.f};

  // one 64-key tile-step (j selects which staged half; diag wave-uniform)
  auto step = [&](int j, bool diag) {
    f32x4 sacc[4];
    #pragma unroll
    for (int i = 0; i < 4; ++i) sacc[i] = (f32x4){0.f, 0.f, 0.f, 0.f};
    __builtin_amdgcn_s_setprio(1);
    #pragma unroll
    for (int s2 = 0; s2 < 2; ++s2) {
      #pragma unroll
      for (int ct = 0; ct < 4; ++ct) {
        if (diag && ct > w) continue;           // fully-masked block, skip
        const bf16x8 bb =
            *(const bf16x8*)&Ks[(j * 64 + ct * 16 + lm) * 72 + s2 * 32 + quad * 8];
        // swapped operands: D[key][q], q = lane&15
        sacc[ct] = __builtin_amdgcn_mfma_f32_16x16x32_bf16(bb, aq[s2], sacc[ct], 0, 0, 0);
      }
    }
    __builtin_amdgcn_s_setprio(0);
    // in-lane softmax: sacc[ct][r] = P[key ct*16+quad*4+r][q w*16+lm]
    unsigned int pd[4][2];
    #pragma unroll
    for (int ct = 0; ct < 4; ++ct) {
      float p[4];
      #pragma unroll
      for (int r = 0; r < 4; ++r) {
        float e;
        if (diag && ct > w) e = 0.f;            // block fully above diagonal
        else {
          e = EXP2F(sacc[ct][r]);
          if (diag && ct == w && (quad * 4 + r) > lm) e = 0.f;  // causal mask
        }
        p[r] = e;
      }
      pd[ct][0] = pk2(p[0], p[1]);
      pd[ct][1] = pk2(p[2], p[3]);
    }
    __builtin_amdgcn_s_setprio(1);
    #pragma unroll
    for (int s2 = 0; s2 < 2; ++s2) {
      if (diag && 2 * s2 > w) continue;         // both ct' blocks masked
      union { bf16x8 v; unsigned int u[4]; } pa;
      pa.u[0] = pd[2 * s2][0];     pa.u[1] = pd[2 * s2][1];
      pa.u[2] = pd[2 * s2 + 1][0]; pa.u[3] = pd[2 * s2 + 1][1];
      lacc = __builtin_amdgcn_mfma_f32_16x16x32_bf16(pa.v, ones, lacc, 0, 0, 0);
      #pragma unroll
      for (int ct = 0; ct < 4; ++ct) {
        const bf16x8 vfr = *(const bf16x8*)&Vts[(ct * 16 + lm) * 136 +
                                                j * 64 + s2 * 32 + quad * 8];
        oacc[ct] = __builtin_amdgcn_mfma_f32_16x16x32_bf16(pa.v, vfr, oacc[ct], 0, 0, 0);
      }
    }
    __builtin_amdgcn_s_setprio(0);
  };

  auto stage = [&](int r2) {
    __syncthreads();                            // prior K/V LDS reads done
    #pragma unroll
    for (int u = 0; u < 4; ++u) {
      const int c = tid + u * 256;
      const int row = c >> 3, c8 = (c & 7) * 8;
      *(bf16x8*)&Ks[row * 72 + c8] = pk[u];
      const int d = c >> 4, c16 = (c & 15) * 8;
      *(bf16x8*)&Vts[d * 136 + c16] = pv[u];
    }
    __syncthreads();
    const int r2n = (r2 + 2 <= qt) ? (r2 + 2) : r2;   // prefetch next pair
    #pragma unroll
    for (int u = 0; u < 4; ++u) {
      const int c = tid + u * 256;
      const int row = c >> 3, c8 = (c & 7) * 8;
      pk[u] = *(const bf16x8*)&kb[(size_t)(r2n * 64 + row) * 64 + c8];
      const int d = c >> 4, c16 = (c & 15) * 8;
      pv[u] = *(const bf16x8*)&vb[(size_t)d * T_ + r2n * 64 + c16];
    }
  };

  int r2 = 0;
  for (; r2 + 1 <= qt; r2 += 2) {               // full pairs only
    stage(r2);
    step(0, false);                             // never diagonal
    step(1, r2 + 1 == qt);                      // diagonal only on last pair
  }
  if (r2 == qt) {                               // peeled final step (even qt)
    stage(r2);
    step(0, true);
  }

  #pragma unroll
  for (int r = 0; r < 4; ++r) {
    const int qrow = q0 + w * 16 + quad * 4 + r;
    const float inv = 1.f / lacc[r];
    // d ct*16+lm -> slot lm*4+ct (WoT k-rows match): one b64 store
    uint2 st;
    st.x = pk2(oacc[0][r] * inv, oacc[1][r] * inv);
    st.y = pk2(oacc[2][r] * inv, oacc[3][r] * inv);
    *(uint2*)&att[((size_t)b * T_ + qrow) * 1024 + h * 64 + lm * 4] = st;
  }
}

// ---------------------------------------------------------------------------
// Kernel 3: output projection [round-6 exact code]: 128x64 tiles, 2-phase
// BK=64 counted-vmcnt loop, XCD-chunked grid 512.
// ---------------------------------------------------------------------------
__global__ __launch_bounds__(256) void outproj_mfma_kernel(
    const short* __restrict__ att, const short* __restrict__ WoT,
    float* __restrict__ out) {
  __shared__ short Xsh[2][128 * 64];
  __shared__ short Wth[2][64 * 64];
  const int tid = threadIdx.x;
  const int lane = tid & 63, w = tid >> 6;
  const int lm = lane & 15, quad = lane >> 4;
  const int bid = blockIdx.x;
  const int xcd = bid & 7, slot = bid >> 3;     // slot 0..63
  const int m0 = (xcd * 4 + (slot & 3)) * 128;
  const int n0 = (slot >> 2) * 64;              // 0..960

  f32x4 acc[2][4];
  #pragma unroll
  for (int sm = 0; sm < 2; ++sm)
    #pragma unroll
    for (int ct = 0; ct < 4; ++ct) acc[sm][ct] = (f32x4){0.f, 0.f, 0.f, 0.f};

  auto stage = [&](int kt, int bsel) {
    #pragma unroll
    for (int u = 0; u < 4; ++u) {
      const int r = u * 32 + w * 8 + (lane >> 3);
      const int sb = (lane & 7) ^ (r & 7);
      g2l16(&att[(size_t)(m0 + r) * 1024 + kt * 64 + sb * 8],
            &Xsh[bsel][(u * 32 + w * 8) * 64]);
    }
    #pragma unroll
    for (int u = 0; u < 2; ++u) {
      const int r = u * 32 + w * 8 + (lane >> 3);
      const int sb = (lane & 7) ^ (r & 7);
      g2l16(&WoT[(size_t)(n0 + r) * 1024 + kt * 64 + sb * 8],
            &Wth[bsel][(u * 32 + w * 8) * 64]);
    }
  };

  stage(0, 0);
  for (int kt = 0; kt < 16; ++kt) {
    const int bsel = kt & 1;
    if (kt < 15) {
      stage(kt + 1, bsel ^ 1);
      asm volatile("s_waitcnt vmcnt(6)" ::: "memory");
    } else {
      asm volatile("s_waitcnt vmcnt(0)" ::: "memory");
    }
    __builtin_amdgcn_s_barrier();
    __builtin_amdgcn_sched_barrier(0);
    #pragma unroll
    for (int s2 = 0; s2 < 2; ++s2) {
      bf16x8 bfr[4];
      #pragma unroll
      for (int ct = 0; ct < 4; ++ct)
        bfr[ct] = *(const bf16x8*)&Wth[bsel][(ct * 16 + lm) * 64 +
                                            (((s2 * 4 + quad) ^ (lm & 7)) << 3)];
      #pragma unroll
      for (int sm = 0; sm < 2; ++sm) {
        const bf16x8 a = *(const bf16x8*)&Xsh[bsel][(w * 32 + sm * 16 + lm) * 64 +
                                            (((s2 * 4 + quad) ^ (lm & 7)) << 3)];
        #pragma unroll
        for (int ct = 0; ct < 4; ++ct)
          acc[sm][ct] =
              __builtin_amdgcn_mfma_f32_16x16x32_bf16(a, bfr[ct], acc[sm][ct], 0, 0, 0);
      }
    }
    __builtin_amdgcn_sched_barrier(0);
    __builtin_amdgcn_s_barrier();
  }

  #pragma unroll
  for (int sm = 0; sm < 2; ++sm)
    #pragma unroll
    for (int r = 0; r < 4; ++r) {
      const int row = m0 + w * 32 + sm * 16 + quad * 4 + r;
      #pragma unroll
      for (int ct = 0; ct < 4; ++ct)
        out[(size_t)row * 1024 + n0 + ct * 16 + lm] = acc[sm][ct][r];
    }
}

extern "C" void kernel_launch(void* const* d_in, const int* in_sizes, int n_in,
                              void* d_out, int out_size, void* d_ws, size_t ws_size,
                              hipStream_t stream) {
  const float* x  = (const float*)d_in[0];
  // d_in[1] = mask: fixed causal tril, handled analytically; never read.
  const float* Wq = (const float*)d_in[2];
  const float* Wk = (const float*)d_in[3];
  const float* Wv = (const float*)d_in[4];
  const float* Wo = (const float*)d_in[5];
  float* out = (float*)d_out;

  short* xb   = (short*)d_ws;
  short* WT   = xb  + (size_t)4194304;          // 1536*1024
  short* WoT  = WT  + (size_t)1572864;          // 1024*1024 (k sigma-permuted)
  short* qb   = WoT + (size_t)1048576;          // 2*16*2048*64 (d sigma-permuted)
  short* kb   = qb  + (size_t)4194304;          // 2*4*2048*64 (d sigma-permuted)
  short* vtb  = kb  + (size_t)1048576;          // 2*4*64*2048 (transposed+permuted)
  short* attb = vtb + (size_t)1048576;          // 2*2048*1024 (d sigma-permuted)
  float2* tbl = (float2*)(attb + (size_t)4194304);  // 2048*32 float2

  prep_kernel<<<dim3(2944), dim3(256), 0, stream>>>(
      x, Wq, Wk, Wv, Wo, xb, WT, WoT, tbl);
  qkv_mfma_kernel<<<dim3(768), dim3(256), 0, stream>>>(xb, WT, tbl, qb, kb, vtb);
  attn_mfma_kernel<<<dim3(1024), dim3(256), 0, stream>>>(qb, kb, vtb, attb);
  outproj_mfma_kernel<<<dim3(512), dim3(256), 0, stream>>>(attb, WoT, out);
}